// Round 4
// baseline (267.096 us; speedup 1.0000x reference)
//
#include <hip/hip_runtime.h>

#define NCH 16
#define HID 128

typedef __attribute__((ext_vector_type(8))) short s16x8;
typedef __attribute__((ext_vector_type(4))) float f32x4;

__device__ __forceinline__ unsigned short f2bf(float f) {
    __bf16 b = (__bf16)f;
    return __builtin_bit_cast(unsigned short, b);
}
__device__ __forceinline__ uint2 pack4(float a, float b, float c, float d) {
    uint2 r;
    r.x = (unsigned)f2bf(a) | ((unsigned)f2bf(b) << 16);
    r.y = (unsigned)f2bf(c) | ((unsigned)f2bf(d) << 16);
    return r;
}

// mfma_f32_16x16x32_bf16 lane maps (verified R2/R3):
//   A-frag: lane l holds A[l%16][8*(l/16)+i]   (i=0..7)
//   B-frag: lane l holds B[8*(l/16)+i][l%16]
//   D:      lane l holds D[4*(l/16)+r][l%16]   (r=0..3)
// GEMM1 (swapped): h^T = wh^T x y^T   -> lane(g,p) gets h[p][16t+4g+r]
// GEMM2 (swapped): dx^T = wo^T x h^T  -> lane(g,p) gets dx[p][4g+r] (epilogue layout)
//
// Pixel mapping (R4): block = 8-row band of one image; wave = 2 rows of the band;
// iteration order (colseg, row-in-pair) so consecutive iters share 2/3 tap rows in L1.
__global__ __launch_bounds__(256, 4) void nca_mfma(
    const float* __restrict__ x,   // [B,H,W,16]
    const float* __restrict__ wh,  // [48,128]
    const float* __restrict__ bh,  // [128]
    const float* __restrict__ wo,  // [128,16]
    const float* __restrict__ ru,  // [B,H,W,1]
    float* __restrict__ out)       // [B,H,W,16]
{
    // LDS union: s_wht [128][72] bf16 (18432 B) live only before the loop;
    // per-wave s_y [4][16][72] (9216 B) + s_h [4][16][136] (17408 B) alias it.
    __shared__ __align__(16) char smem[26624 + 512];
    unsigned short (*s_wht)[72]    = (unsigned short(*)[72])smem;
    unsigned short (*s_y)[16][72]  = (unsigned short(*)[16][72])smem;
    unsigned short (*s_h)[16][136] = (unsigned short(*)[16][136])(smem + 9216);
    float* s_bh = (float*)(smem + 26624);

    const int tid = threadIdx.x;

    // ---- one-time: stage wh transposed to bf16 ----
    for (int idx = tid; idx < 48 * HID; idx += 256) {
        int f = idx >> 7, n = idx & 127;
        s_wht[n][f] = f2bf(wh[idx]);
    }
    for (int idx = tid; idx < HID * 16; idx += 256)
        s_wht[idx >> 4][48 + (idx & 15)] = 0;
    if (tid < HID) s_bh[tid] = bh[tid];
    __syncthreads();

    const int w = tid >> 6, lane = tid & 63;
    const int p = lane & 15, g = lane >> 4;   // p = pixel-in-group, g = quad

    // ---- persistent register fragments ----
    s16x8 whf[2][8];
    #pragma unroll
    for (int t = 0; t < 8; ++t)
        #pragma unroll
        for (int s = 0; s < 2; ++s)
            whf[s][t] = *(const s16x8*)&s_wht[p + 16 * t][s * 32 + 8 * g];

    s16x8 wof[4];
    #pragma unroll
    for (int kk = 0; kk < 4; ++kk) {
        s16x8 v;
        #pragma unroll
        for (int i2 = 0; i2 < 8; ++i2)
            v[i2] = (short)f2bf(wo[(kk * 32 + 8 * g + i2) * NCH + p]);
        wof[kk] = v;
    }
    __syncthreads();   // s_wht dead; s_y/s_h may overwrite it

    // zero this wave's y K-pad (cols 48..63) once
    *(uint2*)&s_y[w][p][48 + 4 * g] = make_uint2(0u, 0u);

    const float4* x4 = (const float4*)x;
    float4* o4 = (float4*)out;
    const float m0 = (g == 0) ? 0.f : 1.f;  // immutable image channels 0..2

    // XCD-aware band swizzle: 512 bands, 8 XCDs, 64 contiguous bands per XCD.
    const int band = (blockIdx.x & 7) * 64 + (blockIdx.x >> 3);   // [0,512)
    const int row0 = band * 8 + w * 2;     // wave's first global row (16*256 rows total)

    #pragma unroll 1
    for (int it = 0; it < 32; ++it) {
        const int rr = it & 1;             // row within the wave's pair
        const int cs = it >> 1;            // column segment [0,16)
        const int R = row0 + rr;           // global row
        const int i = R & 255;             // row within image
        const int j = cs * 16 + p;         // column
        const int pix = R * 256 + j;

        // ---- perceive: lane owns (pixel, channels 4g..4g+3) ----
        const float4 c4 = x4[pix * 4 + g];
        const float fire = (ru[pix] > 0.5f) ? 1.f : 0.f;
        f32x4 sx = {0.f, 0.f, 0.f, 0.f}, sy = {0.f, 0.f, 0.f, 0.f};
        #define NB(di, dj, wx, wy)                                              \
        if ((unsigned)(i + (di)) < 256u && (unsigned)(j + (dj)) < 256u) {       \
            float4 v = x4[(pix + (di) * 256 + (dj)) * 4 + g];                   \
            if ((wx) != 0.f) { sx[0] += (wx) * v.x; sx[1] += (wx) * v.y;        \
                               sx[2] += (wx) * v.z; sx[3] += (wx) * v.w; }      \
            if ((wy) != 0.f) { sy[0] += (wy) * v.x; sy[1] += (wy) * v.y;        \
                               sy[2] += (wy) * v.z; sy[3] += (wy) * v.w; }      \
        }
        NB(-1, -1, -0.125f, -0.125f)
        NB(-1,  0,  0.f,    -0.25f )
        NB(-1,  1,  0.125f, -0.125f)
        NB( 0, -1, -0.25f,   0.f   )
        NB( 0,  1,  0.25f,   0.f   )
        NB( 1, -1, -0.125f,  0.125f)
        NB( 1,  0,  0.f,     0.25f )
        NB( 1,  1,  0.125f,  0.125f)
        #undef NB

        *(uint2*)&s_y[w][p][ 0 + 4 * g] = pack4(c4.x, c4.y, c4.z, c4.w);
        *(uint2*)&s_y[w][p][16 + 4 * g] = pack4(sx[0], sx[1], sx[2], sx[3]);
        *(uint2*)&s_y[w][p][32 + 4 * g] = pack4(sy[0], sy[1], sy[2], sy[3]);

        // ---- GEMM1 (swapped): h^T = wh^T x y^T, acc init = bias ----
        f32x4 acc[8];
        #pragma unroll
        for (int t = 0; t < 8; ++t)
            acc[t] = *(const f32x4*)&s_bh[16 * t + 4 * g];
        #pragma unroll
        for (int s = 0; s < 2; ++s) {
            s16x8 yf = *(const s16x8*)&s_y[w][p][s * 32 + 8 * g];
            #pragma unroll
            for (int t = 0; t < 8; ++t)
                acc[t] = __builtin_amdgcn_mfma_f32_16x16x32_bf16(
                    whf[s][t], yf, acc[t], 0, 0, 0);
        }

        // relu + cvt: lane(g,p) holds h[p][16t+4g+r]
        #pragma unroll
        for (int t = 0; t < 8; ++t) {
            float h0 = fmaxf(acc[t][0], 0.f), h1 = fmaxf(acc[t][1], 0.f);
            float h2 = fmaxf(acc[t][2], 0.f), h3 = fmaxf(acc[t][3], 0.f);
            *(uint2*)&s_h[w][p][16 * t + 4 * g] = pack4(h0, h1, h2, h3);
        }

        // ---- GEMM2 (swapped): dx^T = wo^T x h^T ----
        f32x4 acc2 = {0.f, 0.f, 0.f, 0.f};
        #pragma unroll
        for (int kk = 0; kk < 4; ++kk) {
            s16x8 hf = *(const s16x8*)&s_h[w][p][kk * 32 + 8 * g];
            acc2 = __builtin_amdgcn_mfma_f32_16x16x32_bf16(wof[kk], hf, acc2, 0, 0, 0);
        }

        // ---- epilogue: lane(g,p) already holds dx[pix][4g..4g+3] ----
        float4 o;
        o.x = c4.x + acc2[0] * fire * m0;
        o.y = c4.y + acc2[1] * fire * m0;
        o.z = c4.z + acc2[2] * fire * m0;
        o.w = c4.w + acc2[3] * fire;
        o4[pix * 4 + g] = o;
    }
}

extern "C" void kernel_launch(void* const* d_in, const int* in_sizes, int n_in,
                              void* d_out, int out_size, void* d_ws, size_t ws_size,
                              hipStream_t stream) {
    const float* x  = (const float*)d_in[0];
    const float* wh = (const float*)d_in[1];
    const float* bh = (const float*)d_in[2];
    const float* wo = (const float*)d_in[3];
    const float* ru = (const float*)d_in[4];
    // d_in[5] = steps (==1 from setup_inputs)
    float* out = (float*)d_out;

    // 16 images x 256 rows = 4096 rows; 8-row bands -> 512 blocks
    nca_mfma<<<512, 256, 0, stream>>>(x, wh, bh, wo, ru, out);
}

// Round 5
// 231.426 us; speedup vs baseline: 1.1541x; 1.1541x over previous
//
#include <hip/hip_runtime.h>

#define NCH 16
#define HID 128

typedef __attribute__((ext_vector_type(8))) short s16x8;
typedef __attribute__((ext_vector_type(4))) float f32x4;

__device__ __forceinline__ unsigned short f2bf(float f) {
    __bf16 b = (__bf16)f;
    return __builtin_bit_cast(unsigned short, b);
}
__device__ __forceinline__ unsigned pk2(float a, float b) {
    return (unsigned)f2bf(a) | ((unsigned)f2bf(b) << 16);
}

// mfma_f32_16x16x32_bf16 lane maps (verified R2-R4):
//   A-frag: lane l holds A[l%16][8*(l/16)+i]   (i=0..7)
//   B-frag: lane l holds B[8*(l/16)+i][l%16]
//   D:      lane l holds D[4*(l/16)+r][l%16]   (r=0..3)
//
// K-PERMUTED GEMM1: we reorder wh's 48 features at staging so the B-frag IS the
// perceive's natural register layout (lane(g,p) owns pixel p, channels 4g..4g+3):
//   k = 8g+i (i<4):    center ch 4g+i
//   k = 8g+4+i:        sobel_x ch 4g+i
//   k = 32+8g+i (i<4): sobel_y ch 4g+i
//   k = 36+8g+i:       zero pad
// -> y never touches LDS; feeds MFMA straight from registers.
__global__ __launch_bounds__(256, 3) void nca_mfma(
    const float* __restrict__ x,   // [B,H,W,16]
    const float* __restrict__ wh,  // [48,128]
    const float* __restrict__ bh,  // [128]
    const float* __restrict__ wo,  // [128,16]
    const float* __restrict__ ru,  // [B,H,W,1]
    float* __restrict__ out)       // [B,H,W,16]
{
    // LDS: s_wht [128][72] bf16 (18432 B, transient) aliased by s_h [4][16][136] (17408 B)
    __shared__ __align__(16) char smem[18432 + 512];
    unsigned short (*s_wht)[72]    = (unsigned short(*)[72])smem;
    unsigned short (*s_h)[16][136] = (unsigned short(*)[16][136])smem;
    float* s_bh = (float*)(smem + 18432);

    const int tid = threadIdx.x;

    // ---- one-time: stage wh^T with permuted K ----
    for (int idx = tid; idx < 48 * HID; idx += 256) {
        int f = idx >> 7, n = idx & 127;
        int part = f >> 4, c = f & 15;
        int gg = c >> 2, i2 = c & 3;
        int k = (part == 0) ? (8 * gg + i2)
              : (part == 1) ? (8 * gg + 4 + i2)
                            : (32 + 8 * gg + i2);
        s_wht[n][k] = f2bf(wh[idx]);
    }
    for (int idx = tid; idx < HID * 16; idx += 256) {   // zero the pad slots
        int n = idx >> 4, q = idx & 15;
        s_wht[n][36 + 8 * (q >> 2) + (q & 3)] = 0;
    }
    if (tid < HID) s_bh[tid] = bh[tid];
    __syncthreads();

    const int w = tid >> 6, lane = tid & 63;
    const int p = lane & 15, g = lane >> 4;

    s16x8 whf[2][8];   // persistent A-frags of permuted wh^T
    #pragma unroll
    for (int t = 0; t < 8; ++t)
        #pragma unroll
        for (int s = 0; s < 2; ++s)
            whf[s][t] = *(const s16x8*)&s_wht[p + 16 * t][s * 32 + 8 * g];

    s16x8 wof[4];      // persistent A-frags of wo^T (GEMM2 swapped)
    #pragma unroll
    for (int kk = 0; kk < 4; ++kk) {
        s16x8 v;
        #pragma unroll
        for (int i2 = 0; i2 < 8; ++i2)
            v[i2] = (short)f2bf(wo[(kk * 32 + 8 * g + i2) * NCH + p]);
        wof[kk] = v;
    }
    __syncthreads();   // s_wht dead; s_h may overwrite

    const float4* x4 = (const float4*)x;
    float4* o4 = (float4*)out;
    const float m0 = (g == 0) ? 0.f : 1.f;   // immutable image channels 0..2

    // 1024 4-row bands; XCD swizzle (1024 = 8*128, bijective)
    const int band = (blockIdx.x & 7) * 128 + (blockIdx.x >> 3);
    const int R = band * 4 + w;              // wave owns one global row
    const int i = R & 255;                   // row within image
    const int rowb = R * 256;

    const int   di_t[8] = {-1, -1, -1,  0, 0,  1, 1, 1};
    const int   dj_t[8] = {-1,  0,  1, -1, 1, -1, 0, 1};
    const float wx_t[8] = {-0.125f, 0.f, 0.125f, -0.25f, 0.25f, -0.125f, 0.f, 0.125f};
    const float wy_t[8] = {-0.125f, -0.25f, -0.125f, 0.f, 0.f, 0.125f, 0.25f, 0.125f};

    float4 nbv[8], c4;
    float ruv;

    // batched branchless load issue for column-segment `cs`
    #define ISSUE(cs)                                                            \
    {                                                                            \
        const int j_ = (cs) * 16 + p;                                            \
        const int pix_ = rowb + j_;                                              \
        c4 = x4[pix_ * 4 + g];                                                   \
        ruv = ru[pix_];                                                          \
        _Pragma("unroll")                                                        \
        for (int t = 0; t < 8; ++t) {                                            \
            bool v_ = ((unsigned)(i + di_t[t]) < 256u) &                         \
                      ((unsigned)(j_ + dj_t[t]) < 256u);                         \
            int off_ = v_ ? (di_t[t] * 256 + dj_t[t]) * 4 : 0;                   \
            nbv[t] = x4[pix_ * 4 + g + off_];                                    \
        }                                                                        \
    }

    ISSUE(0)

    #pragma unroll 1
    for (int it = 0; it < 16; ++it) {
        const int j = it * 16 + p;
        const int pix = rowb + j;

        // ---- sobel from prefetched regs (masked weights, branchless) ----
        f32x4 sxv = {0.f, 0.f, 0.f, 0.f}, syv = {0.f, 0.f, 0.f, 0.f};
        #pragma unroll
        for (int t = 0; t < 8; ++t) {
            const bool v = ((unsigned)(i + di_t[t]) < 256u) &
                           ((unsigned)(j + dj_t[t]) < 256u);
            const float4 nv = nbv[t];
            if (wx_t[t] != 0.f) {
                const float wx = v ? wx_t[t] : 0.f;
                sxv[0] += wx * nv.x; sxv[1] += wx * nv.y;
                sxv[2] += wx * nv.z; sxv[3] += wx * nv.w;
            }
            if (wy_t[t] != 0.f) {
                const float wy = v ? wy_t[t] : 0.f;
                syv[0] += wy * nv.x; syv[1] += wy * nv.y;
                syv[2] += wy * nv.z; syv[3] += wy * nv.w;
            }
        }

        // ---- B-frags in-register (permuted-K layout) ----
        s16x8 bf0, bf1;
        {
            unsigned w0 = pk2(c4.x, c4.y), w1 = pk2(c4.z, c4.w);
            unsigned w2 = pk2(sxv[0], sxv[1]), w3 = pk2(sxv[2], sxv[3]);
            unsigned w4 = pk2(syv[0], syv[1]), w5 = pk2(syv[2], syv[3]);
            bf0[0] = (short)(w0 & 0xffff); bf0[1] = (short)(w0 >> 16);
            bf0[2] = (short)(w1 & 0xffff); bf0[3] = (short)(w1 >> 16);
            bf0[4] = (short)(w2 & 0xffff); bf0[5] = (short)(w2 >> 16);
            bf0[6] = (short)(w3 & 0xffff); bf0[7] = (short)(w3 >> 16);
            bf1[0] = (short)(w4 & 0xffff); bf1[1] = (short)(w4 >> 16);
            bf1[2] = (short)(w5 & 0xffff); bf1[3] = (short)(w5 >> 16);
            bf1[4] = 0; bf1[5] = 0; bf1[6] = 0; bf1[7] = 0;
        }
        const float4 c4c = c4;      // keep for epilogue before prefetch clobbers
        const float fire = (ruv > 0.5f) ? 1.f : 0.f;

        // ---- GEMM1 (swapped): h^T = wh^T(perm) x y^T(perm), acc init = bias ----
        f32x4 acc[8];
        #pragma unroll
        for (int t = 0; t < 8; ++t)
            acc[t] = *(const f32x4*)&s_bh[16 * t + 4 * g];
        #pragma unroll
        for (int t = 0; t < 8; ++t)
            acc[t] = __builtin_amdgcn_mfma_f32_16x16x32_bf16(whf[0][t], bf0, acc[t], 0, 0, 0);
        #pragma unroll
        for (int t = 0; t < 8; ++t)
            acc[t] = __builtin_amdgcn_mfma_f32_16x16x32_bf16(whf[1][t], bf1, acc[t], 0, 0, 0);

        // relu + pack h -> LDS (lane(g,p) holds h[p][16t+4g+r])
        #pragma unroll
        for (int t = 0; t < 8; ++t) {
            uint2 hw;
            hw.x = pk2(fmaxf(acc[t][0], 0.f), fmaxf(acc[t][1], 0.f));
            hw.y = pk2(fmaxf(acc[t][2], 0.f), fmaxf(acc[t][3], 0.f));
            *(uint2*)&s_h[w][p][16 * t + 4 * g] = hw;
        }

        // ---- prefetch next iteration's loads (latency hides under GEMM2) ----
        if (it < 15) ISSUE(it + 1)

        // ---- GEMM2 (swapped): dx^T = wo^T x h^T ----
        f32x4 acc2 = {0.f, 0.f, 0.f, 0.f};
        #pragma unroll
        for (int kk = 0; kk < 4; ++kk) {
            s16x8 hf = *(const s16x8*)&s_h[w][p][kk * 32 + 8 * g];
            acc2 = __builtin_amdgcn_mfma_f32_16x16x32_bf16(wof[kk], hf, acc2, 0, 0, 0);
        }

        // ---- epilogue: lane(g,p) holds dx[pix][4g..4g+3] ----
        float4 o;
        o.x = c4c.x + acc2[0] * fire * m0;
        o.y = c4c.y + acc2[1] * fire * m0;
        o.z = c4c.z + acc2[2] * fire * m0;
        o.w = c4c.w + acc2[3] * fire;
        o4[pix * 4 + g] = o;
    }
    #undef ISSUE
}

extern "C" void kernel_launch(void* const* d_in, const int* in_sizes, int n_in,
                              void* d_out, int out_size, void* d_ws, size_t ws_size,
                              hipStream_t stream) {
    const float* x  = (const float*)d_in[0];
    const float* wh = (const float*)d_in[1];
    const float* bh = (const float*)d_in[2];
    const float* wo = (const float*)d_in[3];
    const float* ru = (const float*)d_in[4];
    // d_in[5] = steps (==1 from setup_inputs)
    float* out = (float*)d_out;

    // 4096 global rows / 4-row bands -> 1024 blocks; wave = 1 row x 16 col-segments
    nca_mfma<<<1024, 256, 0, stream>>>(x, wh, bh, wo, ru, out);
}

// Round 6
// 173.970 us; speedup vs baseline: 1.5353x; 1.3303x over previous
//
#include <hip/hip_runtime.h>

#define NCH 16
#define HID 128

typedef __attribute__((ext_vector_type(8))) short s16x8;
typedef __attribute__((ext_vector_type(4))) float f32x4;

__device__ __forceinline__ unsigned short f2bf(float f) {
    __bf16 b = (__bf16)f;
    return __builtin_bit_cast(unsigned short, b);
}
__device__ __forceinline__ unsigned pk2(float a, float b) {
    return (unsigned)f2bf(a) | ((unsigned)f2bf(b) << 16);
}

// mfma_f32_16x16x32_bf16 lane maps (verified R2-R5):
//   A-frag: lane l holds A[l%16][8*(l/16)+i]   (i=0..7)
//   B-frag: lane l holds B[8*(l/16)+i][l%16]
//   D:      lane l holds D[4*(l/16)+r][l%16]   (r=0..3)
// K-permuted GEMM1 (verified R5): wh's features reordered at staging so the
// B-frag is the perceive's natural register layout:
//   k=8g+i (i<4): center ch 4g+i ; k=8g+4+i: sobel_x ch 4g+i
//   k=32+8g+i   : sobel_y ch 4g+i; k=36+8g+i: zero
// GEMM2 swapped: dx^T = wo^T x h^T -> lane(g,p) holds dx[p][4g+r] (epilogue layout)
//
// R6: block = 16x16 image tile; 18x18x16 f32 halo tile staged in LDS (zero-filled
// OOB -> no sobel masks); compute loop has ZERO global loads.
__global__ __launch_bounds__(256, 3) void nca_mfma(
    const float* __restrict__ x,   // [B,H,W,16]
    const float* __restrict__ wh,  // [48,128]
    const float* __restrict__ bh,  // [128]
    const float* __restrict__ wo,  // [128,16]
    const float* __restrict__ ru,  // [B,H,W,1]
    float* __restrict__ out)       // [B,H,W,16]
{
    // LDS: s_x 324px x 20f f32 (25920B) | union{ s_wht 18432B / s_h 17408B } | s_bh
    __shared__ __align__(16) char smem[25920 + 18432 + 512];
    float* s_xf = (float*)smem;                                    // [pp][20]
    unsigned short (*s_wht)[72]    = (unsigned short(*)[72])(smem + 25920);
    unsigned short (*s_h)[16][136] = (unsigned short(*)[16][136])(smem + 25920);
    float* s_bh = (float*)(smem + 25920 + 18432);

    const int tid = threadIdx.x;
    const int w = tid >> 6, lane = tid & 63;
    const int p = lane & 15, g = lane >> 4;

    // block -> (img, tile) with XCD-chunked swizzle (4096 blocks, 8 XCDs, 512 each)
    const int sb   = (blockIdx.x & 7) * 512 + (blockIdx.x >> 3);
    const int img  = sb >> 8, rem = sb & 255;
    const int ti16 = (rem >> 4) << 4;     // tile row origin within image
    const int tj16 = (rem & 15) << 4;     // tile col origin
    const int ibase = img << 16;          // img * 256*256

    const float4* x4 = (const float4*)x;
    float4* o4 = (float4*)out;

    // ---- stage 18x18 halo tile (f32, zero-filled OOB), burst-issued ----
    {
        const int R0 = ti16 - 1, C0 = tj16 - 1;
        for (int idx = tid; idx < 18 * 18 * 4; idx += 256) {
            const int q = idx & 3, pp = idx >> 2;
            const int r = pp / 18, c = pp - r * 18;
            const int ir = R0 + r, jc = C0 + c;
            float4 v = make_float4(0.f, 0.f, 0.f, 0.f);
            if (((unsigned)ir < 256u) & ((unsigned)jc < 256u))
                v = x4[(ibase + (ir << 8) + jc) * 4 + q];
            *(float4*)&s_xf[pp * 20 + 4 * q] = v;
        }
    }

    // ---- ru prefetch for this wave's 4 output rows (reg-resident) ----
    float ruv[4];
    #pragma unroll
    for (int k = 0; k < 4; ++k)
        ruv[k] = ru[ibase + ((ti16 + 4 * w + k) << 8) + tj16 + p];

    // ---- stage wh^T with permuted K + bias ----
    for (int idx = tid; idx < 48 * HID; idx += 256) {
        int f = idx >> 7, n = idx & 127;
        int part = f >> 4, c = f & 15;
        int gg = c >> 2, i2 = c & 3;
        int k = (part == 0) ? (8 * gg + i2)
              : (part == 1) ? (8 * gg + 4 + i2)
                            : (32 + 8 * gg + i2);
        s_wht[n][k] = f2bf(wh[idx]);
    }
    for (int idx = tid; idx < HID * 16; idx += 256) {
        int n = idx >> 4, q = idx & 15;
        s_wht[n][36 + 8 * (q >> 2) + (q & 3)] = 0;
    }
    if (tid < HID) s_bh[tid] = bh[tid];
    __syncthreads();

    // ---- persistent weight fragments ----
    s16x8 whf[2][8];
    #pragma unroll
    for (int t = 0; t < 8; ++t)
        #pragma unroll
        for (int s = 0; s < 2; ++s)
            whf[s][t] = *(const s16x8*)&s_wht[p + 16 * t][s * 32 + 8 * g];

    s16x8 wof[4];
    #pragma unroll
    for (int kk = 0; kk < 4; ++kk) {
        s16x8 v;
        #pragma unroll
        for (int i2 = 0; i2 < 8; ++i2)
            v[i2] = (short)f2bf(wo[(kk * 32 + 8 * g + i2) * NCH + p]);
        wof[kk] = v;
    }
    __syncthreads();   // s_wht dead; s_h may overwrite it

    const float m0 = (g == 0) ? 0.f : 1.f;   // immutable image channels 0..2

    #pragma unroll 2
    for (int k = 0; k < 4; ++k) {
        const int tr = 4 * w + k;                         // tile row (0..15)
        const int pix = ibase + ((ti16 + tr) << 8) + tj16 + p;

        // ---- 9 taps from LDS (pixel stride 20f -> 2-way banks, free) ----
        const float* tp = &s_xf[(tr * 18 + p) * 20 + 4 * g];
        const f32x4 t00 = *(const f32x4*)(tp + 0);
        const f32x4 t01 = *(const f32x4*)(tp + 20);
        const f32x4 t02 = *(const f32x4*)(tp + 40);
        const f32x4 t10 = *(const f32x4*)(tp + 360);
        const f32x4 t11 = *(const f32x4*)(tp + 380);      // center (exact f32)
        const f32x4 t12 = *(const f32x4*)(tp + 400);
        const f32x4 t20 = *(const f32x4*)(tp + 720);
        const f32x4 t21 = *(const f32x4*)(tp + 740);
        const f32x4 t22 = *(const f32x4*)(tp + 760);

        // ---- sobel (no masks; halo pre-zeroed) ----
        f32x4 sxv, syv;
        #pragma unroll
        for (int e = 0; e < 4; ++e) {
            sxv[e] = 0.125f * ((t02[e] - t00[e]) + (t22[e] - t20[e]))
                   + 0.25f  * (t12[e] - t10[e]);
            syv[e] = 0.125f * ((t20[e] - t00[e]) + (t22[e] - t02[e]))
                   + 0.25f  * (t21[e] - t01[e]);
        }

        // ---- B-frags in-register (permuted-K layout) ----
        s16x8 bf0, bf1;
        {
            unsigned w0 = pk2(t11[0], t11[1]), w1 = pk2(t11[2], t11[3]);
            unsigned w2 = pk2(sxv[0], sxv[1]), w3 = pk2(sxv[2], sxv[3]);
            unsigned w4 = pk2(syv[0], syv[1]), w5 = pk2(syv[2], syv[3]);
            bf0[0] = (short)(w0 & 0xffff); bf0[1] = (short)(w0 >> 16);
            bf0[2] = (short)(w1 & 0xffff); bf0[3] = (short)(w1 >> 16);
            bf0[4] = (short)(w2 & 0xffff); bf0[5] = (short)(w2 >> 16);
            bf0[6] = (short)(w3 & 0xffff); bf0[7] = (short)(w3 >> 16);
            bf1[0] = (short)(w4 & 0xffff); bf1[1] = (short)(w4 >> 16);
            bf1[2] = (short)(w5 & 0xffff); bf1[3] = (short)(w5 >> 16);
            bf1[4] = 0; bf1[5] = 0; bf1[6] = 0; bf1[7] = 0;
        }

        // ---- GEMM1 (swapped, permuted): acc init = bias ----
        f32x4 acc[8];
        #pragma unroll
        for (int t = 0; t < 8; ++t)
            acc[t] = *(const f32x4*)&s_bh[16 * t + 4 * g];
        #pragma unroll
        for (int t = 0; t < 8; ++t)
            acc[t] = __builtin_amdgcn_mfma_f32_16x16x32_bf16(whf[0][t], bf0, acc[t], 0, 0, 0);
        #pragma unroll
        for (int t = 0; t < 8; ++t)
            acc[t] = __builtin_amdgcn_mfma_f32_16x16x32_bf16(whf[1][t], bf1, acc[t], 0, 0, 0);

        // ---- relu + pack h -> per-wave LDS ----
        #pragma unroll
        for (int t = 0; t < 8; ++t) {
            uint2 hw;
            hw.x = pk2(fmaxf(acc[t][0], 0.f), fmaxf(acc[t][1], 0.f));
            hw.y = pk2(fmaxf(acc[t][2], 0.f), fmaxf(acc[t][3], 0.f));
            *(uint2*)&s_h[w][p][16 * t + 4 * g] = hw;
        }

        // ---- GEMM2 (swapped): dx^T = wo^T x h^T ----
        f32x4 acc2 = {0.f, 0.f, 0.f, 0.f};
        #pragma unroll
        for (int kk = 0; kk < 4; ++kk) {
            s16x8 hf = *(const s16x8*)&s_h[w][p][kk * 32 + 8 * g];
            acc2 = __builtin_amdgcn_mfma_f32_16x16x32_bf16(wof[kk], hf, acc2, 0, 0, 0);
        }

        // ---- epilogue ----
        const float fire = (ruv[k] > 0.5f) ? 1.f : 0.f;
        float4 o;
        o.x = t11[0] + acc2[0] * fire * m0;
        o.y = t11[1] + acc2[1] * fire * m0;
        o.z = t11[2] + acc2[2] * fire * m0;
        o.w = t11[3] + acc2[3] * fire;
        o4[pix * 4 + g] = o;
    }
}

extern "C" void kernel_launch(void* const* d_in, const int* in_sizes, int n_in,
                              void* d_out, int out_size, void* d_ws, size_t ws_size,
                              hipStream_t stream) {
    const float* x  = (const float*)d_in[0];
    const float* wh = (const float*)d_in[1];
    const float* bh = (const float*)d_in[2];
    const float* wo = (const float*)d_in[3];
    const float* ru = (const float*)d_in[4];
    // d_in[5] = steps (==1 from setup_inputs)
    float* out = (float*)d_out;

    // 16 images x (16x16 tiles of 16x16 px) = 4096 blocks
    nca_mfma<<<4096, 256, 0, stream>>>(x, wh, bh, wo, ru, out);
}